// Round 7
// baseline (196.716 us; speedup 1.0000x reference)
//
#include <hip/hip_runtime.h>
#include <hip/hip_cooperative_groups.h>
#include <stdint.h>

namespace cg = cooperative_groups;

#define BATCH 32
#define NBOX 8192
#define MGT 256
#define NP 8448            // NBOX + MGT = 33 * 256 exactly
#define NUM_SAMP 512
#define NUM_FG 128
#define NBUCK 2048         // histogram buckets = inv >> 12
#define CANDCAP 512        // boundary-bucket candidates (E[count] ~ 4)

__device__ __forceinline__ uint32_t rotl32(uint32_t x, uint32_t r) {
  return (x << r) | (x >> (32u - r));
}

// JAX threefry2x32, key = (0, 42), PARTITIONABLE stream (jax >= 0.4.30
// default): per element f, inputs (x0,x1) = (0, f); 32-bit out = x0' ^ x1'.
__device__ __forceinline__ uint32_t threefry_bits(uint32_t f) {
  uint32_t x0 = 0u;
  uint32_t x1 = f;
  const uint32_t ks0 = 0u, ks1 = 42u;
  const uint32_t ks2 = 0x1BD11BDAu ^ ks0 ^ ks1;
  const uint32_t k[3] = {ks0, ks1, ks2};
  x0 += ks0; x1 += ks1;
  const uint32_t rotA[4] = {13u, 15u, 26u, 6u};
  const uint32_t rotB[4] = {17u, 29u, 16u, 24u};
#pragma unroll
  for (int g = 0; g < 5; ++g) {
#pragma unroll
    for (int q = 0; q < 4; ++q) {
      uint32_t rr = (g & 1) ? rotB[q] : rotA[q];
      x0 += x1; x1 = rotl32(x1, rr); x1 ^= x0;
    }
    x0 += k[(g + 1) % 3];
    x1 += k[(g + 2) % 3] + (uint32_t)(g + 1);
  }
  return x0 ^ x1;
}

struct ShA {  // phase A: gt row staging (5.1 KB)
  float4 sg[MGT];
  float sga[MGT];
  int nv;
};
struct ShB {  // phase B: select+sort state (~20.5 KB)
  uint32_t hist[NBUCK];                 // packed pos<<16 | neg
  unsigned long long cand[2][CANDCAP];
  unsigned long long sk[NUM_SAMP];
  uint32_t wsum[4];
  int candn[2], cutb[2], rem[2], npos, selcnt;
};
union ShU { ShA a; ShB b; };

__device__ __forceinline__ void emit_lds(unsigned long long* __restrict__ sk,
                                         int* __restrict__ cnt,
                                         uint32_t idx, uint32_t inv) {
  // Final ordering key = fl(2.0f + r) descending, ties ascending index.
  uint32_t mant = 0x7FFFFFu - inv;
  float r = __uint_as_float(0x3F800000u | mant) - 1.0f;
  float score = __fadd_rn(2.0f, r);
  uint32_t sb = __float_as_uint(score);
  unsigned long long key =
      ((unsigned long long)(~sb) << 14) | (unsigned long long)idx;
  int slot = atomicAdd(cnt, 1);
  if (slot < NUM_SAMP) sk[slot] = key;
}

// Fused cooperative kernel.  Phase A (all 33x32 blocks): IoU argmax gated by
// exact RN(i/u)>=0.5 predicate + threefry, 1 box/thread (proven R5 config —
// 4+ blocks/CU hides the LDS broadcast latency chain; 4-box blocking at 288
// blocks regressed to 6% occupancy).  grid.sync().  Phase B (blockIdx.x==0,
// 32 blocks): histogram radix-select + bitonic sort + gather.
// __launch_bounds__(256,5): >=5 blocks/CU guaranteed => 1280 >= 1056 grid,
// cooperative residency check passes (LDS 20.5KB*5=103KB<160KB, VGPR<=102).
__global__ __launch_bounds__(256, 5) void fused_roi(
    const float* __restrict__ boxes, const float* __restrict__ gt_boxes,
    const int* __restrict__ gt_classes, uint32_t* __restrict__ packed,
    int* __restrict__ midx_ws, float* __restrict__ out) {
  __shared__ ShU sh;
  const int tid = threadIdx.x;

  // ---------------- Phase A ----------------
  {
    const int b = blockIdx.y;
    const int i = blockIdx.x * 256 + tid;  // 33*256 == NP, always in range
    if (tid == 0) sh.a.nv = MGT;
    __syncthreads();
    {
      float4 g = ((const float4*)gt_boxes)[b * MGT + tid];  // 256 thr == MGT
      sh.a.sg[tid] = g;
      sh.a.sga[tid] = __fmul_rn(__fsub_rn(g.z, g.x), __fsub_rn(g.w, g.y));
      if (g.x < 0.0f) atomicMin(&sh.a.nv, tid);  // invalid rows are all -1
    }
    __syncthreads();
    const int nv = sh.a.nv;

    float4 bx;
    if (i < NBOX) bx = ((const float4*)boxes)[b * NBOX + i];
    else          bx = ((const float4*)gt_boxes)[b * MGT + (i - NBOX)];
    const float area_b = __fmul_rn(__fsub_rn(bx.z, bx.x), __fsub_rn(bx.w, bx.y));

    const double CHALF = 0.5 - 0x1p-26;  // RN(i/u) >= 0.5 <=> i >= u*CHALF
    float bestq = -1.0f;
    int bestj = -1;
#pragma unroll 4
    for (int j = 0; j < nv; ++j) {
      float4 g = sh.a.sg[j];  // uniform j -> LDS broadcast, conflict-free
      float iy0 = fmaxf(bx.x, g.x);
      float ix0 = fmaxf(bx.y, g.y);
      float iy1 = fminf(bx.z, g.z);
      float ix1 = fminf(bx.w, g.w);
      float ih = fmaxf(__fsub_rn(iy1, iy0), 0.0f);
      float iw = fmaxf(__fsub_rn(ix1, ix0), 0.0f);
      float inter = __fmul_rn(ih, iw);
      if (inter > 0.0f) {  // ~0.5% of pairs per lane
        float u = __fsub_rn(__fadd_rn(area_b, sh.a.sga[j]), inter);  // u > 0
        if ((double)inter >= (double)u * CHALF) {  // exact: RN(i/u) >= 0.5
          float q = __fdiv_rn(inter, u);           // IEEE RN, matches jnp
          if (q > bestq) { bestq = q; bestj = j; } // strict > == first-max
        }
      }
    }

    const bool pos = (bestj >= 0);
    const uint32_t bits = threefry_bits((uint32_t)(b * NP + i));
    const uint32_t mant = bits >> 9;          // r = mant * 2^-23 exactly
    const uint32_t inv = 0x7FFFFFu - mant;    // ascending inv == descending r
    packed[b * NP + i] = (inv << 1) | (pos ? 1u : 0u);
    midx_ws[b * NP + i] = bestj;              // background -> -1
  }

  cg::this_grid().sync();  // device-scope fence: packed/midx visible grid-wide
  if (blockIdx.x != 0) return;

  // ---------------- Phase B (32 blocks, one per batch row) ----------------
  const int b = blockIdx.y;
  const uint32_t* __restrict__ rowp = packed + b * NP;

  if (tid == 0) { sh.b.selcnt = 0; sh.b.candn[0] = 0; sh.b.candn[1] = 0; }
  for (int k = tid; k < NBUCK; k += 256) sh.b.hist[k] = 0;
  sh.b.sk[tid] = ~0ull;
  sh.b.sk[tid + 256] = ~0ull;
  __syncthreads();

  for (int idx = tid; idx < NP; idx += 256) {  // histogram straight from L2
    uint32_t w = rowp[idx];
    atomicAdd(&sh.b.hist[(w >> 1) >> 12], (w & 1u) ? 0x10000u : 1u);
  }
  __syncthreads();

  // packed scan over 2048 buckets: 8 buckets/thread chunk, shfl intra-wave
  const int base = tid * 8;
  uint32_t csum = 0;
#pragma unroll
  for (int q = 0; q < 8; ++q) csum += sh.b.hist[base + q];
  uint32_t incl = csum;
#pragma unroll
  for (int d = 1; d < 64; d <<= 1) {
    uint32_t v = __shfl_up(incl, d, 64);
    if ((tid & 63) >= d) incl += v;
  }
  const int wid = tid >> 6;  // 4 waves
  if ((tid & 63) == 63) sh.b.wsum[wid] = incl;
  __syncthreads();
  {
    uint32_t prefix = 0;
#pragma unroll
    for (int w = 0; w < 4; ++w) prefix += (w < wid) ? sh.b.wsum[w] : 0u;
    incl += prefix;
  }
  const uint32_t excl = incl - csum;
  if (tid == 255) {
    const int tpos = (int)(incl >> 16);
    const int tneg = (int)(incl & 0xFFFFu);
    sh.b.npos = tpos;
    if (tpos < NUM_FG) { sh.b.cutb[1] = NBUCK; sh.b.rem[1] = 0; }  // take all
    const int npc = (tpos < NUM_FG) ? tpos : NUM_FG;
    const int Ln = NUM_SAMP - npc;
    if (Ln == 0)        { sh.b.cutb[0] = -1;    sh.b.rem[0] = 0; }
    else if (tneg < Ln) { sh.b.cutb[0] = NBUCK; sh.b.rem[0] = 0; }
  }
  __syncthreads();
  {  // positive cutoff walk (limit 128)
    const uint32_t L = NUM_FG;
    uint32_t pe = excl >> 16, pi = incl >> 16;
    if (pe < L && pi >= L) {
      uint32_t run = pe;
#pragma unroll
      for (int q = 0; q < 8; ++q) {
        uint32_t h = sh.b.hist[base + q] >> 16;
        if (run + h >= L) { sh.b.cutb[1] = base + q; sh.b.rem[1] = (int)(L - run); break; }
        run += h;
      }
    }
  }
  {  // negative cutoff walk (limit 512 - min(npos,128))
    const int npc = (sh.b.npos < NUM_FG) ? sh.b.npos : NUM_FG;
    const uint32_t L = (uint32_t)(NUM_SAMP - npc);
    uint32_t ne = excl & 0xFFFFu, ni = incl & 0xFFFFu;
    if (L > 0 && ne < L && ni >= L) {
      uint32_t run = ne;
#pragma unroll
      for (int q = 0; q < 8; ++q) {
        uint32_t h = sh.b.hist[base + q] & 0xFFFFu;
        if (run + h >= L) { sh.b.cutb[0] = base + q; sh.b.rem[0] = (int)(L - run); break; }
        run += h;
      }
    }
  }
  __syncthreads();

  // Selection: below cutoff -> emit; at cutoff -> candidate for exact rank.
  for (int idx = tid; idx < NP; idx += 256) {
    uint32_t w = rowp[idx];
    uint32_t f = w & 1u;
    uint32_t inv = w >> 1;
    int bk = (int)(inv >> 12);
    if (bk < sh.b.cutb[f]) {
      emit_lds(sh.b.sk, &sh.b.selcnt, (uint32_t)idx, inv);
    } else if (bk == sh.b.cutb[f]) {
      int s = atomicAdd(&sh.b.candn[f], 1);
      if (s < CANDCAP)
        sh.b.cand[f][s] =
            ((unsigned long long)inv << 14) | (unsigned long long)idx;
    }
  }
  __syncthreads();

  for (int f = 0; f < 2; ++f) {  // exact (inv,idx)-rank inside boundary bucket
    int n = sh.b.candn[f]; if (n > CANDCAP) n = CANDCAP;
    for (int c = tid; c < n; c += 256) {
      unsigned long long me = sh.b.cand[f][c];
      int r = 0;
      for (int j = 0; j < n; ++j) r += (sh.b.cand[f][j] < me) ? 1 : 0;
      if (r < sh.b.rem[f])
        emit_lds(sh.b.sk, &sh.b.selcnt, (uint32_t)(me & 0x3FFFull),
                 (uint32_t)(me >> 14));
    }
  }

  // Bitonic sort of 512 keys, 256 threads (2 elems/thread).  j<=32 rounds are
  // wave-local (pair lanes tid, tid^j share a wave64) -> wave fence only.
  bool prevCross = true;  // selection emits were cross-wave
  for (int k = 2; k <= NUM_SAMP; k <<= 1) {
    for (int j = k >> 1; j > 0; j >>= 1) {
      const bool cross = (j >= 64);
      if (cross || prevCross) __syncthreads();
      else __builtin_amdgcn_wave_barrier();
#pragma unroll
      for (int p = 0; p < 2; ++p) {
        const int t = tid + p * 256, ixj = t ^ j;
        if (ixj > t) {
          unsigned long long a = sh.b.sk[t], c = sh.b.sk[ixj];
          bool asc = ((t & k) == 0);
          if ((a > c) == asc) { sh.b.sk[t] = c; sh.b.sk[ixj] = a; }
        }
      }
      prevCross = cross;
    }
  }
  __syncthreads();

  const int gtb_base = BATCH * NUM_SAMP * 4;        // 65536
  const int cls_base = 2 * BATCH * NUM_SAMP * 4;    // 131072
  const int idx_base = cls_base + BATCH * NUM_SAMP; // 147456

  for (int t = tid; t < NUM_SAMP; t += 256) {
    unsigned long long key = sh.b.sk[t];
    int i = (int)(key & 0x3FFFull);
    if (i >= NP) i = NP - 1;  // defensive
    float4 roi;
    if (i < NBOX) roi = ((const float4*)boxes)[b * NBOX + i];
    else          roi = ((const float4*)gt_boxes)[b * MGT + (i - NBOX)];
    const int o4 = (b * NUM_SAMP + t) * 4;
    out[o4 + 0] = roi.x;
    out[o4 + 1] = roi.y;
    out[o4 + 2] = roi.z;
    out[o4 + 3] = roi.w;

    const int midx = midx_ws[b * NP + i];
    float4 gb = make_float4(0.0f, 0.0f, 0.0f, 0.0f);
    float cls = 0.0f;
    if (midx >= 0) {
      gb = ((const float4*)gt_boxes)[b * MGT + midx];
      cls = (float)gt_classes[b * MGT + midx];
    }
    out[gtb_base + o4 + 0] = gb.x;
    out[gtb_base + o4 + 1] = gb.y;
    out[gtb_base + o4 + 2] = gb.z;
    out[gtb_base + o4 + 3] = gb.w;
    out[cls_base + b * NUM_SAMP + t] = cls;
    out[idx_base + b * NUM_SAMP + t] = (float)midx;  // -1 for background
  }
}

extern "C" void kernel_launch(void* const* d_in, const int* in_sizes, int n_in,
                              void* d_out, int out_size, void* d_ws, size_t ws_size,
                              hipStream_t stream) {
  const float* boxes      = (const float*)d_in[0];  // (32,8192,4) f32
  const float* gt_boxes   = (const float*)d_in[1];  // (32,256,4)  f32
  const int*   gt_classes = (const int*)d_in[2];    // (32,256)    i32
  float* out = (float*)d_out;

  char* ws = (char*)d_ws;
  // layout: packed u32[32][8448] | midx i32[32][8448]
  uint32_t* packed = (uint32_t*)(ws);
  int* midx_ws     = (int*)(ws + 1081344);

  void* args[] = {(void*)&boxes, (void*)&gt_boxes, (void*)&gt_classes,
                  (void*)&packed, (void*)&midx_ws, (void*)&out};
  hipLaunchCooperativeKernel((const void*)fused_roi, dim3(NP / 256, BATCH),
                             dim3(256), args, 0, stream);
}

// Round 8
// 105.294 us; speedup vs baseline: 1.8683x; 1.8683x over previous
//
#include <hip/hip_runtime.h>
#include <stdint.h>

#define BATCH 32
#define NBOX 8192
#define MGT 256
#define NP 8448            // NBOX + MGT = 33 * 256
#define NUM_SAMP 512
#define NUM_FG 128
#define NBUCK 2048         // histogram buckets = inv >> 12
#define CANDCAP 1024       // boundary-bucket candidate capacity (E[count] ~ 4)

__device__ __forceinline__ uint32_t rotl32(uint32_t x, uint32_t r) {
  return (x << r) | (x >> (32u - r));
}

// JAX threefry2x32, key = (0, 42), PARTITIONABLE stream (jax >= 0.4.30
// default): per element f, inputs (x0,x1) = (0, f); 32-bit out = x0' ^ x1'.
__device__ __forceinline__ uint32_t threefry_bits(uint32_t f) {
  uint32_t x0 = 0u;
  uint32_t x1 = f;
  const uint32_t ks0 = 0u, ks1 = 42u;
  const uint32_t ks2 = 0x1BD11BDAu ^ ks0 ^ ks1;
  const uint32_t k[3] = {ks0, ks1, ks2};
  x0 += ks0; x1 += ks1;
  const uint32_t rotA[4] = {13u, 15u, 26u, 6u};
  const uint32_t rotB[4] = {17u, 29u, 16u, 24u};
#pragma unroll
  for (int g = 0; g < 5; ++g) {
#pragma unroll
    for (int q = 0; q < 4; ++q) {
      uint32_t rr = (g & 1) ? rotB[q] : rotA[q];
      x0 += x1; x1 = rotl32(x1, rr); x1 ^= x0;
    }
    x0 += k[(g + 1) % 3];
    x1 += k[(g + 2) % 3] + (uint32_t)(g + 1);
  }
  return x0 ^ x1;
}

// K1: per (b,i) find first-argmax of RN(inter/union) restricted to candidates
// with RN(q) >= 0.5 (exact predicate i >= u*(0.5-2^-26), exact in f64).
// 1 box/thread, 33x32 grid (proven: 4+ blocks/CU hides LDS broadcast latency;
// 4-box blocking regressed to 6% occupancy).  Only ONE ds_read_b128 per gt
// iteration — gt area computed inline inside the rare overlap branch.
__global__ __launch_bounds__(256) void k1_compute(const float* __restrict__ boxes,
                                                  const float* __restrict__ gt_boxes,
                                                  uint32_t* __restrict__ packed,
                                                  int* __restrict__ midx_ws) {
  const int b = blockIdx.y;
  const int i = blockIdx.x * 256 + threadIdx.x;  // 33*256 == NP, in range
  __shared__ float4 sg[MGT];
  __shared__ int nv_s;        // valid-gt prefix length (invalid = -1 tail)
  if (threadIdx.x == 0) nv_s = MGT;
  __syncthreads();
  {
    float4 g = ((const float4*)gt_boxes)[b * MGT + threadIdx.x];  // 256 == MGT
    sg[threadIdx.x] = g;
    if (g.x < 0.0f) atomicMin(&nv_s, threadIdx.x);  // invalid rows all -1
  }
  __syncthreads();
  const int nv = nv_s;

  float4 bx;
  if (i < NBOX) bx = ((const float4*)boxes)[b * NBOX + i];
  else          bx = ((const float4*)gt_boxes)[b * MGT + (i - NBOX)];
  const float area_b = __fmul_rn(__fsub_rn(bx.z, bx.x), __fsub_rn(bx.w, bx.y));

  const double CHALF = 0.5 - 0x1p-26;  // RN(i/u) >= 0.5  <=>  i >= u*CHALF
  float bestq = -1.0f;
  int bestj = -1;
#pragma unroll 4
  for (int j = 0; j < nv; ++j) {
    float4 g = sg[j];  // uniform j -> LDS broadcast, conflict-free
    float iy0 = fmaxf(bx.x, g.x);
    float ix0 = fmaxf(bx.y, g.y);
    float iy1 = fminf(bx.z, g.z);
    float ix1 = fminf(bx.w, g.w);
    float ih = fmaxf(__fsub_rn(iy1, iy0), 0.0f);
    float iw = fmaxf(__fsub_rn(ix1, ix0), 0.0f);
    float inter = __fmul_rn(ih, iw);
    if (inter > 0.0f) {  // ~2% of pairs per lane
      float ag = __fmul_rn(__fsub_rn(g.z, g.x), __fsub_rn(g.w, g.y));
      float u = __fsub_rn(__fadd_rn(area_b, ag), inter);  // u > 0
      if ((double)inter >= (double)u * CHALF) {  // exact: RN(i/u) >= 0.5
        float q = __fdiv_rn(inter, u);           // IEEE RN, matches jnp
        if (q > bestq) { bestq = q; bestj = j; } // strict > == first-max
      }
    }
  }

  const bool pos = (bestj >= 0);
  const uint32_t bits = threefry_bits((uint32_t)(b * NP + i));
  const uint32_t mant = bits >> 9;          // r = mant * 2^-23 exactly
  const uint32_t inv = 0x7FFFFFu - mant;    // ascending inv == descending r
  packed[b * NP + i] = (inv << 1) | (pos ? 1u : 0u);
  midx_ws[b * NP + i] = bestj;              // background -> -1
}

__device__ __forceinline__ void emit_lds(unsigned long long* __restrict__ sk,
                                         int* __restrict__ cnt,
                                         uint32_t idx, uint32_t inv) {
  // Final ordering key = fl(2.0f + r) descending, ties ascending index.
  uint32_t mant = 0x7FFFFFu - inv;
  float r = __uint_as_float(0x3F800000u | mant) - 1.0f;
  float score = __fadd_rn(2.0f, r);
  uint32_t sb = __float_as_uint(score);
  unsigned long long key =
      ((unsigned long long)(~sb) << 14) | (unsigned long long)idx;
  int slot = atomicAdd(cnt, 1);
  if (slot < NUM_SAMP) sk[slot] = key;
}

// K23: per-row O(n) histogram radix-select (rank by ascending (inv, idx),
// class-limit 128 fg / 512-min(npos,128) bg) + 512-key bitonic sort + gather.
// Row data read straight from L2 (uint4, 4 loads in flight) — no LDS staging.
// Histograms for both classes packed in one u32 (pos<<16 | neg).
__global__ __launch_bounds__(512) void k23_select_sort_gather(
    const uint32_t* __restrict__ packed, const float* __restrict__ boxes,
    const float* __restrict__ gt_boxes, const int* __restrict__ gt_classes,
    const int* __restrict__ midx_ws, float* __restrict__ out) {
  const int b = blockIdx.x;
  const int tid = threadIdx.x;
  __shared__ uint32_t hist[NBUCK];                 // 8192 B, packed
  __shared__ uint32_t wsum[8];
  __shared__ unsigned long long cand[2][CANDCAP];  // 16384 B
  __shared__ unsigned long long sk[NUM_SAMP];      // 4096 B
  __shared__ int candn[2];
  __shared__ int cutb[2], rem[2];
  __shared__ int npos_s, selcnt_s;

  const uint4* __restrict__ rowp4 = (const uint4*)(packed + b * NP);

  if (tid == 0) { selcnt_s = 0; candn[0] = 0; candn[1] = 0; }
  for (int k = tid; k < NBUCK; k += 512) hist[k] = 0;
  if (tid < NUM_SAMP) sk[tid] = ~0ull;
  __syncthreads();

  for (int k4 = tid; k4 < NP / 4; k4 += 512) {  // histogram from L2
    uint4 w = rowp4[k4];
    atomicAdd(&hist[(w.x >> 1) >> 12], (w.x & 1u) ? 0x10000u : 1u);
    atomicAdd(&hist[(w.y >> 1) >> 12], (w.y & 1u) ? 0x10000u : 1u);
    atomicAdd(&hist[(w.z >> 1) >> 12], (w.z & 1u) ? 0x10000u : 1u);
    atomicAdd(&hist[(w.w >> 1) >> 12], (w.w & 1u) ? 0x10000u : 1u);
  }
  __syncthreads();

  // --- packed scan over 2048 buckets: 4 buckets/thread chunk ---
  const int base = tid * 4;
  uint32_t csum = 0;
#pragma unroll
  for (int q = 0; q < 4; ++q) csum += hist[base + q];
  uint32_t incl = csum;
#pragma unroll
  for (int d = 1; d < 64; d <<= 1) {  // intra-wave inclusive scan
    uint32_t v = __shfl_up(incl, d, 64);
    if ((tid & 63) >= d) incl += v;
  }
  const int wid = tid >> 6;
  if ((tid & 63) == 63) wsum[wid] = incl;
  __syncthreads();
  {
    uint32_t prefix = 0;
#pragma unroll
    for (int w = 0; w < 8; ++w) prefix += (w < wid) ? wsum[w] : 0u;
    incl += prefix;
  }
  const uint32_t excl = incl - csum;
  if (tid == 511) {
    const int tpos = (int)(incl >> 16);
    const int tneg = (int)(incl & 0xFFFFu);
    npos_s = tpos;
    if (tpos < NUM_FG) { cutb[1] = NBUCK; rem[1] = 0; }  // take all positives
    const int npc = (tpos < NUM_FG) ? tpos : NUM_FG;
    const int Ln = NUM_SAMP - npc;
    if (Ln == 0)        { cutb[0] = -1;    rem[0] = 0; }  // take no negatives
    else if (tneg < Ln) { cutb[0] = NBUCK; rem[0] = 0; }  // take all negatives
  }
  __syncthreads();
  {  // positive cutoff walk (limit 128)
    const uint32_t L = NUM_FG;
    uint32_t pe = excl >> 16, pi = incl >> 16;
    if (pe < L && pi >= L) {
      uint32_t run = pe;
#pragma unroll
      for (int q = 0; q < 4; ++q) {
        uint32_t h = hist[base + q] >> 16;
        if (run + h >= L) { cutb[1] = base + q; rem[1] = (int)(L - run); break; }
        run += h;
      }
    }
  }
  {  // negative cutoff walk (limit 512 - min(npos,128))
    const int npc = (npos_s < NUM_FG) ? npos_s : NUM_FG;
    const uint32_t L = (uint32_t)(NUM_SAMP - npc);
    uint32_t ne = excl & 0xFFFFu, ni = incl & 0xFFFFu;
    if (L > 0 && ne < L && ni >= L) {
      uint32_t run = ne;
#pragma unroll
      for (int q = 0; q < 4; ++q) {
        uint32_t h = hist[base + q] & 0xFFFFu;
        if (run + h >= L) { cutb[0] = base + q; rem[0] = (int)(L - run); break; }
        run += h;
      }
    }
  }
  __syncthreads();

  // Selection: below cutoff -> emit; at cutoff -> candidate for exact rank.
  for (int k4 = tid; k4 < NP / 4; k4 += 512) {
    uint4 wv = rowp4[k4];
    const uint32_t ws[4] = {wv.x, wv.y, wv.z, wv.w};
#pragma unroll
    for (int c = 0; c < 4; ++c) {
      uint32_t w = ws[c];
      uint32_t f = w & 1u;
      uint32_t inv = w >> 1;
      int bk = (int)(inv >> 12);
      if (bk < cutb[f]) {
        emit_lds(sk, &selcnt_s, (uint32_t)(k4 * 4 + c), inv);
      } else if (bk == cutb[f]) {
        int s = atomicAdd(&candn[f], 1);
        if (s < CANDCAP)
          cand[f][s] = ((unsigned long long)inv << 14) |
                       (unsigned long long)(k4 * 4 + c);
      }
    }
  }
  __syncthreads();

  for (int f = 0; f < 2; ++f) {  // exact (inv,idx)-rank inside boundary bucket
    int n = candn[f]; if (n > CANDCAP) n = CANDCAP;
    for (int c = tid; c < n; c += 512) {
      unsigned long long me = cand[f][c];
      int r = 0;
      for (int j = 0; j < n; ++j) r += (cand[f][j] < me) ? 1 : 0;
      if (r < rem[f])
        emit_lds(sk, &selcnt_s, (uint32_t)(me & 0x3FFFull),
                 (uint32_t)(me >> 14));
    }
  }

  // Bitonic sort of 512 keys; j<=32 rounds are wave-local (partner lane =
  // lane^j within the same wave64) -> compiler fence only, no block barrier.
  bool prevCross = true;  // selection emits were cross-wave
  for (int k = 2; k <= NUM_SAMP; k <<= 1) {
    for (int j = k >> 1; j > 0; j >>= 1) {
      const bool cross = (j >= 64);
      if (cross || prevCross) __syncthreads();
      else __builtin_amdgcn_wave_barrier();
      const int t = tid, ixj = t ^ j;
      if (ixj > t) {
        unsigned long long a = sk[t], c = sk[ixj];
        bool asc = ((t & k) == 0);
        if ((a > c) == asc) { sk[t] = c; sk[ixj] = a; }
      }
      prevCross = cross;
    }
  }
  __syncthreads();

  const int gtb_base = BATCH * NUM_SAMP * 4;        // 65536
  const int cls_base = 2 * BATCH * NUM_SAMP * 4;    // 131072
  const int idx_base = cls_base + BATCH * NUM_SAMP; // 147456

  for (int t = tid; t < NUM_SAMP; t += 512) {
    unsigned long long key = sk[t];
    int i = (int)(key & 0x3FFFull);
    if (i >= NP) i = NP - 1;  // defensive
    float4 roi;
    if (i < NBOX) roi = ((const float4*)boxes)[b * NBOX + i];
    else          roi = ((const float4*)gt_boxes)[b * MGT + (i - NBOX)];
    const int o4 = (b * NUM_SAMP + t) * 4;
    out[o4 + 0] = roi.x;
    out[o4 + 1] = roi.y;
    out[o4 + 2] = roi.z;
    out[o4 + 3] = roi.w;

    const int midx = midx_ws[b * NP + i];
    float4 gb = make_float4(0.0f, 0.0f, 0.0f, 0.0f);
    float cls = 0.0f;
    if (midx >= 0) {
      gb = ((const float4*)gt_boxes)[b * MGT + midx];
      cls = (float)gt_classes[b * MGT + midx];
    }
    out[gtb_base + o4 + 0] = gb.x;
    out[gtb_base + o4 + 1] = gb.y;
    out[gtb_base + o4 + 2] = gb.z;
    out[gtb_base + o4 + 3] = gb.w;
    out[cls_base + b * NUM_SAMP + t] = cls;
    out[idx_base + b * NUM_SAMP + t] = (float)midx;  // -1 for background
  }
}

extern "C" void kernel_launch(void* const* d_in, const int* in_sizes, int n_in,
                              void* d_out, int out_size, void* d_ws, size_t ws_size,
                              hipStream_t stream) {
  const float* boxes      = (const float*)d_in[0];  // (32,8192,4) f32
  const float* gt_boxes   = (const float*)d_in[1];  // (32,256,4)  f32
  const int*   gt_classes = (const int*)d_in[2];    // (32,256)    i32
  float* out = (float*)d_out;

  char* ws = (char*)d_ws;
  // layout: packed u32[32][8448] | midx i32[32][8448]
  uint32_t* packed = (uint32_t*)(ws);
  int* midx_ws     = (int*)(ws + 1081344);

  k1_compute<<<dim3(NP / 256, BATCH), 256, 0, stream>>>(boxes, gt_boxes, packed,
                                                        midx_ws);
  k23_select_sort_gather<<<BATCH, 512, 0, stream>>>(packed, boxes, gt_boxes,
                                                    gt_classes, midx_ws, out);
}